// Round 2
// baseline (216.716 us; speedup 1.0000x reference)
//
#include <hip/hip_runtime.h>

// CTC loss forward (sum reduction). Shapes fixed: T=1000, B=64, V=512, S=100.
// PRODUCER/CONSUMER fused kernel: one block (4 waves) per batch element b.
//   - Waves 1..3 (producers), round-robin over chunks (owner p = c%3):
//       window c-3: issue 16x global_load_lds(16B) for chunk c -> sr[c%3]
//       window c-1: vmcnt(0); gather 24 cols from sr; fmaf+exp2; write
//                   compact float4{eb,e1,e3,0} per (row,lane) -> cp[c&1];
//                   lgkmcnt(0).
//     Gather + transcendental preprocessing is OFF the serial critical path.
//   - Wave 0 (consumer), window j: ONE asm batch of 8x ds_read_b128 from
//     cp[j&1] (contiguous 1KB/row -> conflict-free) + 8 recursion steps
//     (linear domain, 2^5/step scale, DPP renorm every 2 windows).
//   - Sync: ONE raw s_barrier per window (NOT __syncthreads - that drains
//     producer DMA queues). LDS race ledger:
//       sr[c%3]: DMA-written (windows c-3..c-1), read at gather (window c-1,
//                by the SAME wave that re-issues it for chunk c+3 at window c).
//       cp[c&1]: written window c-1 (drained pre-barrier), read window c,
//                next write window c+1 - barrier-separated.
//   - LDS: 3 x 8 x 2048 B staging + 2 x 8 x 1024 B compact = 64 KiB exactly.

#define NEGF (-1e30f)

constexpr int CT_T  = 1000;
constexpr int CT_B  = 64;
constexpr int CT_V  = 512;
constexpr int CT_S  = 100;
constexpr int CT_Se = 201;
constexpr float LOG2E = 1.4426950408889634f;
constexpr float LN2   = 0.6931471805599453f;
constexpr float SHIFT = 5.0f;

typedef float f4 __attribute__((ext_vector_type(4)));

#if __has_builtin(__builtin_amdgcn_exp2f) && __has_builtin(__builtin_amdgcn_logf)
__device__ __forceinline__ float fexp2(float x) { return __builtin_amdgcn_exp2f(x); }
__device__ __forceinline__ float flog2(float x) { return __builtin_amdgcn_logf(x); }
__device__ __forceinline__ float frcp(float x)  { return __builtin_amdgcn_rcpf(x); }
#else
__device__ __forceinline__ float fexp2(float x) { return exp2f(x); }
__device__ __forceinline__ float flog2(float x) { return log2f(x); }
__device__ __forceinline__ float frcp(float x)  { return 1.0f / x; }
#endif

__device__ __forceinline__ float lae2_b2(float x, float y) {
    float m = fmaxf(x, y);
    float d = fminf(x, y) - m;
    return m + flog2(1.0f + fexp2(d));
}
__device__ __forceinline__ float lae3_b2(float x, float y, float z) {
    float m = fmaxf(fmaxf(x, y), z);
    float s = fexp2(x - m) + fexp2(y - m) + fexp2(z - m);
    return m + flog2(s);
}

// lane l <- lane l-1 (lane 0 <- 0): DPP wave_shr:1, VALU speed.
__device__ __forceinline__ float wave_shr1(float x) {
    return __int_as_float(__builtin_amdgcn_update_dpp(
        0, __float_as_int(x), 0x138, 0xf, 0xf, true));
}
// wave max of NON-NEGATIVE x, all-VALU DPP reduce; uniform via readlane 63.
__device__ __forceinline__ float wave_max_nonneg(float x) {
#define DPPMAX(ctrl) x = fmaxf(x, __int_as_float(__builtin_amdgcn_update_dpp( \
        0, __float_as_int(x), ctrl, 0xf, 0xf, true)))
    DPPMAX(0x111); DPPMAX(0x112); DPPMAX(0x114); DPPMAX(0x118);
    DPPMAX(0x142); DPPMAX(0x143);
#undef DPPMAX
    return __int_as_float(__builtin_amdgcn_readlane(__float_as_int(x), 63));
}

typedef const __attribute__((address_space(1))) unsigned int* as1_uint_ptr;
typedef __attribute__((address_space(3))) unsigned int* as3_uint_ptr;
__device__ __forceinline__ void gld16(const void* g, void* l) {
    __builtin_amdgcn_global_load_lds((as1_uint_ptr)g, (as3_uint_ptr)l, 16, 0, 0);
}

// ---------------- fused recursion, producer/consumer + compact handoff ------
__global__ __launch_bounds__(256, 1) void ctc_alpha(
    const float* __restrict__ logp,    // (T, B, V)
    const int*   __restrict__ in_len,
    const int*   __restrict__ tgt,
    const int*   __restrict__ tgt_len,
    float*       __restrict__ loss_ws)
{
    __shared__ __align__(16) float sr[3][8][CT_V];   // 48 KiB staging
    __shared__ __align__(16) float cp[2][8][256];    // 16 KiB compact (f4/lane)

    const int b    = blockIdx.x;
    const int tid  = threadIdx.x;
    const int wv   = tid >> 6;           // 0 = consumer, 1..3 = producers
    const int lane = tid & 63;
    const int Tin  = in_len[b];
    const int Lt   = tgt_len[b];
    const int lim  = 2 * Lt + 1;
    const int* tg  = tgt + b * CT_S;

    const int K = (Tin - 1 + 7) / 8;     // total chunks (>= 63 for Tin >= 500)

    const int s0 = 4 * lane, s1 = s0 + 1, s3 = s0 + 3;
    const int i1 = min((s1 - 1) >> 1, CT_S - 1);
    const int i3 = min((s3 - 1) >> 1, CT_S - 1);
    const int c1 = tg[i1];
    const int c3 = tg[i3];
    const float sk1 = ((s1 >= 3) && (s1 < CT_Se) && (c1 != tg[max(i1 - 1, 0)])) ? 1.f : 0.f;
    const float sk3 = ((s3 >= 3) && (s3 < CT_Se) && (c3 != tg[max(i3 - 1, 0)])) ? 1.f : 0.f;
    const float m0 = (s0     < lim) ? 1.f : 0.f;
    const float m1 = (s0 + 1 < lim) ? 1.f : 0.f;
    const float m2 = (s0 + 2 < lim) ? 1.f : 0.f;
    const float m3 = (s0 + 3 < lim) ? 1.f : 0.f;

    float a0 = 0.f, a1 = 0.f, a2 = 0.f, a3 = 0.f, pa3 = 0.f;
    if (tid == 0) {
        const float* r0 = logp + (size_t)b * CT_V;
        a0 = fexp2(fmaf(r0[1], LOG2E, SHIFT));
        if (Lt > 0) a1 = fexp2(fmaf(r0[c1], LOG2E, SHIFT));
    }
    float rs = 0.f;   // accumulated renorm log2-scale (wave-uniform)

    // ---- producer: DMA chunk k's 8 rows into sr[k%3]
    auto issue = [&](int k) {
        const int tb = 1 + 8 * k;
        const int buf = k % 3;
        #pragma unroll
        for (int i = 0; i < 8; ++i) {
            const int t = min(tb + i, CT_T - 1);
            const char* g = (const char*)(logp + ((size_t)t * CT_B + b) * CT_V)
                          + (size_t)lane * 16;
            gld16(g,        &sr[buf][i][0]);
            gld16(g + 1024, &sr[buf][i][256]);
        }
    };

    // ---- producer: gather + exp2 chunk c from sr[c%3] -> compact cp[c&1]
    // Caller invariant: this wave's ONLY outstanding DMAs are chunk c's 16.
    auto pgather = [&](int c) {
        asm volatile("s_waitcnt vmcnt(0)" ::: "memory");
        __builtin_amdgcn_sched_barrier(0);
        const int sb = c % 3, cb = c & 1;
        #pragma unroll
        for (int i = 0; i < 8; ++i) {
            float gb = sr[sb][i][1];     // blank col (broadcast)
            float g1 = sr[sb][i][c1];
            float g3 = sr[sb][i][c3];
            f4 v;
            v.x = fexp2(fmaf(gb, LOG2E, SHIFT));
            v.y = fexp2(fmaf(g1, LOG2E, SHIFT));
            v.z = fexp2(fmaf(g3, LOG2E, SHIFT));
            v.w = 0.f;
            reinterpret_cast<f4*>(&cp[cb][i][0])[lane] = v;   // ds_write_b128
        }
        asm volatile("s_waitcnt lgkmcnt(0)" ::: "memory");    // drain pre-barrier
        __builtin_amdgcn_sched_barrier(0);
    };

    auto renorm = [&]() {
        float lm = wave_max_nonneg(fmaxf(fmaxf(a0, a1), fmaxf(a2, a3)));
        if (lm > 0.f) {
            float sc = frcp(lm);
            rs += flog2(lm);
            a0 *= sc; a1 *= sc; a2 *= sc; a3 *= sc;
            pa3 = wave_shr1(a3);
        }
    };

    // ---- consumer: one window = 8 pre-exponentiated steps from cp[cb]
    auto run8 = [&](int cb, int tb, bool guard) {
        unsigned base = (unsigned)(size_t)(&cp[cb][0][0]) + 16u * (unsigned)lane;
        f4 e[8];
        asm volatile(
            "ds_read_b128 %0, %8 offset:0\n\t"
            "ds_read_b128 %1, %8 offset:1024\n\t"
            "ds_read_b128 %2, %8 offset:2048\n\t"
            "ds_read_b128 %3, %8 offset:3072\n\t"
            "ds_read_b128 %4, %8 offset:4096\n\t"
            "ds_read_b128 %5, %8 offset:5120\n\t"
            "ds_read_b128 %6, %8 offset:6144\n\t"
            "ds_read_b128 %7, %8 offset:7168\n\t"
            "s_waitcnt lgkmcnt(0)"
            : "=&v"(e[0]), "=&v"(e[1]), "=&v"(e[2]), "=&v"(e[3]),
              "=&v"(e[4]), "=&v"(e[5]), "=&v"(e[6]), "=&v"(e[7])
            : "v"(base));
        #pragma unroll
        for (int i = 0; i < 8; ++i) {
            float ex = e[i].x * m0, ey = e[i].y * m1;
            float ez = e[i].x * m2, ew = e[i].z * m3;
            float n0 = (a0 + pa3) * ex;
            float n1 = fmaf(sk1, pa3, a1 + a0) * ey;
            float n2 = (a2 + a1) * ez;
            float n3 = fmaf(sk3, a1, a3 + a2) * ew;
            if (!guard || (tb + i < Tin)) { a0 = n0; a1 = n1; a2 = n2; a3 = n3; }
            pa3 = wave_shr1(a3);
        }
    };

    // ---- prologue: producers pre-issue chunks 0..2; p0 pre-gathers chunk 0
    if (wv) {
        const int p = wv - 1;
        if (p < K) issue(p);
        if (p == 0) pgather(0);          // compact chunk 0 ready at barrier_0
    }
    __builtin_amdgcn_s_barrier();        // barrier_0

    // ---- main loop: one window per chunk, one raw barrier per window
    for (int j = 0; j < K; ++j) {
        if (wv == 0) {
            run8(j & 1, 1 + 8 * j, j == K - 1);
            if (j & 1) renorm();
        } else {
            const int p = wv - 1;
            // gather chunk j+1 (owner (j+1)%3) -> cp[(j+1)&1], consumer-safe:
            // cp[(j+1)&1] was last READ at window j-1 (barrier-separated).
            if (((j + 1) % 3) == p && (j + 1) < K) pgather(j + 1);
            // issue chunk j+3 (owner (j+3)%3 == j%3) into sr[j%3], which this
            // SAME wave finished gathering (chunk j) at window j-1.
            if ((j % 3) == p && (j + 3) < K) issue(j + 3);
        }
        __builtin_amdgcn_s_barrier();    // barrier_{j+1}
    }

    if (wv) {                            // producers: drain & exit
        asm volatile("s_waitcnt vmcnt(0)" ::: "memory");
        return;
    }

    // ---- consumer epilogue
    const int last = 2 * Lt;
    const int prev = max(last - 1, 0);
    const int lr = last & 3, lidx = last >> 2;
    float av = (lr == 0) ? a0 : (lr == 1) ? a1 : (lr == 2) ? a2 : a3;
    float a_last = __shfl(av, lidx);
    const int pr = prev & 3, pidx = prev >> 2;
    float pv = (pr == 0) ? a0 : (pr == 1) ? a1 : (pr == 2) ? a2 : a3;
    float a_prev = __shfl(pv, pidx);

    float sum = a_last + a_prev;
    float loss = 0.f;
    if (sum > 0.f)
        loss = -(flog2(sum) + rs - SHIFT * (float)Tin) * LN2;
    if (lane == 0) loss_ws[b] = loss;
}

// ---------------- Fallback (log-domain single pass) ----------------
__global__ __launch_bounds__(64) void ctc_alpha_fb(
    const float* __restrict__ logp, const int* __restrict__ in_len,
    const int* __restrict__ tgt, const int* __restrict__ tgt_len,
    float* __restrict__ loss_ws)
{
    const int b = blockIdx.x, lane = threadIdx.x;
    const int Tin = in_len[b], Lt = tgt_len[b];
    const int ext_len = 2 * Lt + 1;
    const int* tg = tgt + b * CT_S;
    const int s0 = 4 * lane, s1 = s0 + 1, s3 = s0 + 3;
    const int i1 = min((s1 - 1) >> 1, CT_S - 1);
    const int i3 = min((s3 - 1) >> 1, CT_S - 1);
    const int c1 = tg[i1], c3 = tg[i3];
    const bool skip1 = (s1 >= 3) && (s1 < CT_Se) && (c1 != tg[max(i1 - 1, 0)]);
    const bool skip3 = (s3 >= 3) && (s3 < CT_Se) && (c3 != tg[max(i3 - 1, 0)]);
    const bool v0 = s0 < ext_len, v1 = s1 < ext_len;
    const bool v2 = (s0 + 2) < ext_len, v3 = s3 < ext_len;
    const float* row0 = logp + (long long)b * CT_V;
    const long long stride = (long long)CT_B * CT_V;
    float a0 = NEGF, a1 = NEGF, a2 = NEGF, a3 = NEGF;
    if (lane == 0) {
        a0 = row0[1] * LOG2E;
        if (ext_len > 1) a1 = row0[c1] * LOG2E;
    }
    float3 E0, E1, E2, E3;
    auto ld = [&](float3& e, int t) {
        int tt = min(t, CT_T - 1);
        const float* r = row0 + (long long)tt * stride;
        e.x = r[1] * LOG2E; e.y = r[c1] * LOG2E; e.z = r[c3] * LOG2E;
    };
    auto step = [&](const float3& e) {
        float pa3 = __shfl_up(a3, 1);
        if (lane == 0) pa3 = NEGF;
        float z1 = skip1 ? pa3 : NEGF;
        float z3 = skip3 ? a1 : NEGF;
        float n0 = v0 ? lae2_b2(a0, pa3)    + e.x : NEGF;
        float n1 = v1 ? lae3_b2(a1, a0, z1) + e.y : NEGF;
        float n2 = v2 ? lae2_b2(a2, a1)     + e.x : NEGF;
        float n3 = v3 ? lae3_b2(a3, a2, z3) + e.z : NEGF;
        a0 = n0; a1 = n1; a2 = n2; a3 = n3;
    };
    ld(E0, 1); ld(E1, 2); ld(E2, 3); ld(E3, 4);
    for (int t = 1; t < Tin; t += 4) {
        step(E0); ld(E0, t + 4);
        if (t + 1 < Tin) { step(E1); ld(E1, t + 5); }
        if (t + 2 < Tin) { step(E2); ld(E2, t + 6); }
        if (t + 3 < Tin) { step(E3); ld(E3, t + 7); }
    }
    const int last = 2 * Lt, prev = max(last - 1, 0);
    const int lr = last & 3, lidx = last >> 2;
    float av = (lr == 0) ? a0 : (lr == 1) ? a1 : (lr == 2) ? a2 : a3;
    float a_last = __shfl(av, lidx);
    const int pr = prev & 3, pidx = prev >> 2;
    float pv = (pr == 0) ? a0 : (pr == 1) ? a1 : (pr == 2) ? a2 : a3;
    float a_prev = __shfl(pv, pidx);
    float loglik = lae2_b2(a_last, a_prev) * LN2;
    float loss = (loglik < 0.5f * NEGF) ? 0.0f : -loglik;
    if (lane == 0) loss_ws[b] = loss;
}

__global__ __launch_bounds__(64) void ctc_sum(const float* __restrict__ loss_ws,
                                              float* __restrict__ out)
{
    float v = loss_ws[threadIdx.x];
    #pragma unroll
    for (int o = 32; o > 0; o >>= 1) v += __shfl_down(v, o);
    if (threadIdx.x == 0) out[0] = v;
}

extern "C" void kernel_launch(void* const* d_in, const int* in_sizes, int n_in,
                              void* d_out, int out_size, void* d_ws, size_t ws_size,
                              hipStream_t stream) {
    const float* logp    = (const float*)d_in[0];
    const int*   in_len  = (const int*)d_in[1];
    const int*   tgt     = (const int*)d_in[2];
    const int*   tgt_len = (const int*)d_in[3];
    float* out = (float*)d_out;
    float* loss_ws = (float*)d_ws;   // needs only 256 B

    if (ws_size >= 256 * sizeof(float)) {
        hipLaunchKernelGGL(ctc_alpha, dim3(CT_B), dim3(256), 0, stream,
                           logp, in_len, tgt, tgt_len, loss_ws);
    } else {
        hipLaunchKernelGGL(ctc_alpha_fb, dim3(CT_B), dim3(64), 0, stream,
                           logp, in_len, tgt, tgt_len, loss_ws);
    }
    hipLaunchKernelGGL(ctc_sum, dim3(1), dim3(64), 0, stream, loss_ws, out);
}